// Round 1
// baseline (18769.698 us; speedup 1.0000x reference)
//
#include <hip/hip_runtime.h>
#include <stdint.h>

#define B 32
#define S 64
#define T 32
#define E 300
#define HE 256
#define HD 512
#define VD 50000
#define GE 768
#define GD 1536
#define CATN 812
#define SOS 2
#define EOS 3

// ---------------- ws layout (float offsets) ----------------
#define SZ_WIHT3   (E*HE*3)        // 230400
#define SZ_WHHT3   (HE*HE*3)       // 196608
#define SZ_WATTNT4 (CATN*HD)       // 415744
#define SZ_WIHDT3  (CATN*HD*3)     // 1247232
#define SZ_WHHDT3  (HD*HD*3)       // 786432
#define SZ_GI      (S*B*HE*3)      // 1572864
#define SZ_ENCOUT  (B*S*HD)        // 1048576

constexpr size_t OFF_WIHT3F  = 0;
constexpr size_t OFF_WIHT3B  = OFF_WIHT3F + SZ_WIHT3 + 4;
constexpr size_t OFF_WHHT3F  = OFF_WIHT3B + SZ_WIHT3 + 4;
constexpr size_t OFF_WHHT3B  = OFF_WHHT3F + SZ_WHHT3 + 4;
constexpr size_t OFF_WATTNT4 = OFF_WHHT3B + SZ_WHHT3 + 4;
constexpr size_t OFF_WIHDT3  = OFF_WATTNT4 + SZ_WATTNT4;
constexpr size_t OFF_WHHDT3  = OFF_WIHDT3 + SZ_WIHDT3 + 4;
constexpr size_t OFF_GIF     = OFF_WHHDT3 + SZ_WHHDT3 + 4;
constexpr size_t OFF_GIB     = OFF_GIF + SZ_GI + 4;
constexpr size_t OFF_ENCOUT  = OFF_GIB + SZ_GI + 4;
constexpr size_t OFF_HBUF    = OFF_ENCOUT + SZ_ENCOUT;
constexpr size_t OFF_QBUF    = OFF_HBUF + B*HD;
constexpr size_t OFF_GHBUF   = OFF_QBUF + B*HD;      // [3][B][HD]
constexpr size_t OFF_GIEBUF  = OFF_GHBUF + 3*B*HD;   // [3][B][HD]
constexpr size_t OFF_CTXBUF  = OFF_GIEBUF + 3*B*HD;
constexpr size_t OFF_EXPSUM  = OFF_CTXBUF + B*HD;    // [T][B]
constexpr size_t OFF_LSE     = OFF_EXPSUM + T*B;     // [T][B]
constexpr size_t OFF_PACKED  = OFF_LSE + T*B;        // u64 [T][B]

// ---------------- d_out layout ----------------
constexpr size_t O_LOGP = 0;
constexpr size_t O_IDX  = (size_t)B*T*VD;     // 51200000
constexpr size_t O_MASK = O_IDX + B*T;
constexpr size_t O_ATT  = O_MASK + B*T;

struct __align__(4) f4u { float x, y, z, w; };
__device__ __forceinline__ f4u ld4u(const float* p) { return *(const f4u*)p; }

__device__ __forceinline__ float sigm(float x) { return 1.0f / (1.0f + __expf(-x)); }
__device__ __forceinline__ float tanhfast(float x) {
    float e = __expf(2.0f * fminf(x, 15.0f));
    return (e - 1.0f) / (e + 1.0f);
}

// ---------------- K0: weight repack + scratch zero ----------------
__global__ __launch_bounds__(256) void k_prep(
    const float* __restrict__ Wihf, const float* __restrict__ Whhf,
    const float* __restrict__ Wihb, const float* __restrict__ Whhb,
    const float* __restrict__ Wihd, const float* __restrict__ Whhd,
    const float* __restrict__ Wattn, float* __restrict__ ws)
{
    const size_t NWIH = (size_t)GE * E;
    const size_t NWHH = (size_t)GE * HE;
    const size_t NATT = (size_t)HD * CATN;
    const size_t NWID = (size_t)GD * CATN;
    const size_t NWHD = (size_t)GD * HD;
    size_t i = (size_t)blockIdx.x * 256 + threadIdx.x;

    if (i < 2 * NWIH) {
        int d = i >= NWIH;
        size_t r = i - (d ? NWIH : 0);
        int row = (int)(r / E), k = (int)(r - (size_t)row * E);
        int g = row >> 8, j = row & 255;
        const float* src = d ? Wihb : Wihf;
        ws[(d ? OFF_WIHT3B : OFF_WIHT3F) + ((size_t)k * HE + j) * 3 + g] = src[r];
        return;
    }
    i -= 2 * NWIH;
    if (i < 2 * NWHH) {
        int d = i >= NWHH;
        size_t r = i - (d ? NWHH : 0);
        int row = (int)(r / HE), k = (int)(r & (HE - 1));
        int g = row >> 8, j = row & 255;
        const float* src = d ? Whhb : Whhf;
        ws[(d ? OFF_WHHT3B : OFF_WHHT3F) + ((size_t)k * HE + j) * 3 + g] = src[r];
        return;
    }
    i -= 2 * NWHH;
    if (i < NATT) {
        int row = (int)(i / CATN), k = (int)(i - (size_t)row * CATN);
        ws[OFF_WATTNT4 + (((size_t)(k >> 2) * HD + row) << 2) + (k & 3)] = Wattn[i];
        return;
    }
    i -= NATT;
    if (i < NWID) {
        int row = (int)(i / CATN), k = (int)(i - (size_t)row * CATN);
        int g = row >> 9, j = row & 511;
        ws[OFF_WIHDT3 + ((size_t)k * HD + j) * 3 + g] = Wihd[i];
        return;
    }
    i -= NWID;
    if (i < NWHD) {
        int row = (int)(i / HD), k = (int)(i & (HD - 1));
        int g = row >> 9, j = row & 511;
        ws[OFF_WHHDT3 + ((size_t)k * HD + j) * 3 + g] = Whhd[i];
        return;
    }
    i -= NWHD;
    if (i < 4096) ws[OFF_EXPSUM + i] = 0.0f;   // expsum + lse + packedmax
}

// ---------------- K1: encoder input gates gi = x@Wih.T + bih (both dirs) ----------------
__global__ __launch_bounds__(256) void k_enc_gi(
    const int* __restrict__ data, const float* __restrict__ emb_enc,
    const float* __restrict__ bihf, const float* __restrict__ bihb,
    float* __restrict__ ws)
{
    int s = blockIdx.x, dir = blockIdx.y, b0 = blockIdx.z * 16;
    int tid = threadIdx.x;
    __shared__ float xT[E * 16];   // [k][bb]
    int s_eff = dir ? (S - 1 - s) : s;
    for (int idx = tid; idx < 16 * E; idx += 256) {
        int bb = idx / E, k = idx - bb * E;
        int tok = data[(b0 + bb) * S + s_eff];
        xT[k * 16 + bb] = emb_enc[(size_t)tok * E + k];
    }
    __syncthreads();
    const float* W3 = ws + (dir ? OFF_WIHT3B : OFF_WIHT3F);
    const float* bih = dir ? bihb : bihf;
    int j = tid;
    float aR[16], aZ[16], aN[16];
#pragma unroll
    for (int bb = 0; bb < 16; bb++) { aR[bb] = 0.f; aZ[bb] = 0.f; aN[bb] = 0.f; }
    for (int k = 0; k < E; k++) {
        f4u w = ld4u(W3 + ((size_t)k * HE + j) * 3);
        const float* xk = &xT[k * 16];
#pragma unroll
        for (int bb = 0; bb < 16; bb++) {
            float x = xk[bb];
            aR[bb] += x * w.x; aZ[bb] += x * w.y; aN[bb] += x * w.z;
        }
    }
    float br = bih[j], bz = bih[HE + j], bn = bih[2 * HE + j];
    float* gi = ws + (dir ? OFF_GIB : OFF_GIF);
#pragma unroll
    for (int bb = 0; bb < 16; bb++) {
        size_t base = (((size_t)s * B + b0 + bb) * HE + j) * 3;
        gi[base + 0] = aR[bb] + br;
        gi[base + 1] = aZ[bb] + bz;
        gi[base + 2] = aN[bb] + bn;
    }
}

// ---------------- K2: encoder recurrence, one WG per (batch, dir) ----------------
__global__ __launch_bounds__(256) void k_enc_rec(
    const float* __restrict__ bhhf, const float* __restrict__ bhhb,
    float* __restrict__ ws)
{
    int b = blockIdx.x, dir = blockIdx.y, j = threadIdx.x;
    __shared__ float h[HE];
    h[j] = 0.f;
    __syncthreads();
    const float* W3 = ws + (dir ? OFF_WHHT3B : OFF_WHHT3F);
    const float* gi = ws + (dir ? OFF_GIB : OFF_GIF);
    const float* bhh = dir ? bhhb : bhhf;
    float* enc = ws + OFF_ENCOUT;
    float br = bhh[j], bz = bhh[HE + j], bn = bhh[2 * HE + j];
    for (int s = 0; s < S; s++) {
        float gr = br, gz = bz, gn = bn;
#pragma unroll 4
        for (int k4 = 0; k4 < HE / 4; k4++) {
            float4 h4 = *(const float4*)&h[k4 * 4];
#pragma unroll
            for (int kk = 0; kk < 4; kk++) {
                int k = k4 * 4 + kk;
                f4u w = ld4u(W3 + ((size_t)k * HE + j) * 3);
                float hv = (kk == 0) ? h4.x : (kk == 1) ? h4.y : (kk == 2) ? h4.z : h4.w;
                gr += hv * w.x; gz += hv * w.y; gn += hv * w.z;
            }
        }
        f4u g = ld4u(gi + (((size_t)s * B + b) * HE + j) * 3);
        float hold = h[j];
        float r = sigm(g.x + gr);
        float z = sigm(g.y + gz);
        float n = tanhfast(g.z + r * gn);
        float hn = (1.f - z) * n + z * hold;
        __syncthreads();
        h[j] = hn;
        int s_store = dir ? (S - 1 - s) : s;
        enc[((size_t)b * S + s_store) * HD + dir * HE + j] = hn;
        if (s == S - 1) ws[OFF_HBUF + (size_t)b * HD + dir * HE + j] = hn;
        __syncthreads();
    }
}

__device__ __forceinline__ int decode_inp(const float* ws, int t, int b) {
    if (t == 0) return SOS;
    const unsigned long long* pm = (const unsigned long long*)(ws + OFF_PACKED);
    unsigned long long p = pm[(size_t)(t - 1) * B + b];
    return (VD - 1) - (int)(unsigned)(p & 0xffffffffu);
}

// ---------------- D1: q = cat(emb,h)@Wattn.T ; gh = h@Whhd.T ; giE = emb@Wihd[:, :E].T ----------------
__global__ __launch_bounds__(256) void k_dec1(
    const float* __restrict__ emb_dec, const float* __restrict__ battn,
    const float* __restrict__ bhhd, const float* __restrict__ bihd,
    float* __restrict__ ws, int t)
{
    int b = blockIdx.x, chunk = blockIdx.y, tid = threadIdx.x;
    __shared__ float cat[CATN + 4];
    int inp = decode_inp(ws, t, b);
    const float* hb = ws + OFF_HBUF + (size_t)b * HD;
    for (int k = tid; k < CATN; k += 256)
        cat[k] = (k < E) ? emb_dec[(size_t)inp * E + k] : hb[k - E];
    __syncthreads();

    if (chunk < 2) {             // q
        int i = chunk * 256 + tid;
        float acc = battn[i];
        const float* W4 = ws + OFF_WATTNT4;
        for (int k4 = 0; k4 < CATN / 4; k4++) {
            float4 c4 = *(const float4*)&cat[k4 * 4];
            float4 w4 = *(const float4*)&W4[((size_t)k4 * HD + i) << 2];
            acc += c4.x * w4.x + c4.y * w4.y + c4.z * w4.z + c4.w * w4.w;
        }
        ws[OFF_QBUF + (size_t)b * HD + i] = acc;
    } else if (chunk < 4) {      // gh
        int jj = (chunk - 2) * 256 + tid;
        float gr = bhhd[jj], gz = bhhd[HD + jj], gn = bhhd[2 * HD + jj];
        const float* W3 = ws + OFF_WHHDT3;
        for (int k4 = 0; k4 < HD / 4; k4++) {
            float4 h4 = *(const float4*)&cat[E + k4 * 4];
#pragma unroll
            for (int kk = 0; kk < 4; kk++) {
                f4u w = ld4u(W3 + ((size_t)(k4 * 4 + kk) * HD + jj) * 3);
                float hv = (kk == 0) ? h4.x : (kk == 1) ? h4.y : (kk == 2) ? h4.z : h4.w;
                gr += hv * w.x; gz += hv * w.y; gn += hv * w.z;
            }
        }
        float* gh = ws + OFF_GHBUF;
        gh[0 * B * HD + (size_t)b * HD + jj] = gr;
        gh[1 * B * HD + (size_t)b * HD + jj] = gz;
        gh[2 * B * HD + (size_t)b * HD + jj] = gn;
    } else {                     // giE (emb part of decoder GRU input gates)
        int jj = (chunk - 4) * 256 + tid;
        float gr = bihd[jj], gz = bihd[HD + jj], gn = bihd[2 * HD + jj];
        const float* W3 = ws + OFF_WIHDT3;
        for (int k4 = 0; k4 < E / 4; k4++) {
            float4 x4 = *(const float4*)&cat[k4 * 4];
#pragma unroll
            for (int kk = 0; kk < 4; kk++) {
                f4u w = ld4u(W3 + ((size_t)(k4 * 4 + kk) * HD + jj) * 3);
                float xv = (kk == 0) ? x4.x : (kk == 1) ? x4.y : (kk == 2) ? x4.z : x4.w;
                gr += xv * w.x; gz += xv * w.y; gn += xv * w.z;
            }
        }
        float* ge = ws + OFF_GIEBUF;
        ge[0 * B * HD + (size_t)b * HD + jj] = gr;
        ge[1 * B * HD + (size_t)b * HD + jj] = gz;
        ge[2 * B * HD + (size_t)b * HD + jj] = gn;
    }
}

// ---------------- D2: scores -> softmax -> ctx (one wave per batch row) ----------------
__global__ __launch_bounds__(64) void k_dec_attn(
    float* __restrict__ ws, float* __restrict__ out, int t)
{
    int b = blockIdx.x, s = threadIdx.x;
    __shared__ float q[HD];
    __shared__ float awl[S];
    const float* qb = ws + OFF_QBUF + (size_t)b * HD;
    for (int k = s; k < HD; k += 64) q[k] = qb[k];
    __syncthreads();
    const float* enc = ws + OFF_ENCOUT + ((size_t)b * S + s) * HD;
    float sc = 0.f;
    for (int k4 = 0; k4 < HD / 4; k4++) {
        float4 q4 = *(const float4*)&q[k4 * 4];
        float4 e4 = *(const float4*)&enc[k4 * 4];
        sc += q4.x * e4.x + q4.y * e4.y + q4.z * e4.z + q4.w * e4.w;
    }
    float m = sc;
    for (int off = 32; off; off >>= 1) m = fmaxf(m, __shfl_xor(m, off));
    float e = __expf(sc - m);
    float sum = e;
    for (int off = 32; off; off >>= 1) sum += __shfl_xor(sum, off);
    float aw = e / sum;
    out[O_ATT + ((size_t)b * T + t) * S + s] = aw;
    awl[s] = aw;
    __syncthreads();
    const float* encb = ws + OFF_ENCOUT + (size_t)b * S * HD;
    float* ctx = ws + OFF_CTXBUF + (size_t)b * HD;
    for (int jj = 0; jj < HD / 64; jj++) {
        int jIdx = jj * 64 + s;
        float acc = 0.f;
        for (int ss = 0; ss < S; ss++) acc += awl[ss] * encb[(size_t)ss * HD + jIdx];
        ctx[jIdx] = acc;
    }
}

// ---------------- D3: giC = ctx@Wihd[:, E:].T ; gates -> h2 ----------------
__global__ __launch_bounds__(256) void k_dec3(float* __restrict__ ws, int t)
{
    int jc = blockIdx.x, bg = blockIdx.y;
    int tid = threadIdx.x;
    int jl = tid & 31, bb = tid >> 5;
    int j = jc * 32 + jl, b = bg * 8 + bb;
    __shared__ float xc[8 * HD];
    for (int idx = tid; idx < 8 * HD; idx += 256) {
        int bbb = idx >> 9, k = idx & 511;
        xc[idx] = ws[OFF_CTXBUF + (size_t)(bg * 8 + bbb) * HD + k];
    }
    __syncthreads();
    const float* W3 = ws + OFF_WIHDT3;
    float gr = ws[OFF_GIEBUF + 0 * B * HD + (size_t)b * HD + j];
    float gz = ws[OFF_GIEBUF + 1 * B * HD + (size_t)b * HD + j];
    float gn = ws[OFF_GIEBUF + 2 * B * HD + (size_t)b * HD + j];
    const float* xrow = &xc[bb * HD];
    for (int k4 = 0; k4 < HD / 4; k4++) {
        float4 x4 = *(const float4*)&xrow[k4 * 4];
#pragma unroll
        for (int kk = 0; kk < 4; kk++) {
            f4u w = ld4u(W3 + ((size_t)(E + k4 * 4 + kk) * HD + j) * 3);
            float xv = (kk == 0) ? x4.x : (kk == 1) ? x4.y : (kk == 2) ? x4.z : x4.w;
            gr += xv * w.x; gz += xv * w.y; gn += xv * w.z;
        }
    }
    float ghr = ws[OFF_GHBUF + 0 * B * HD + (size_t)b * HD + j];
    float ghz = ws[OFF_GHBUF + 1 * B * HD + (size_t)b * HD + j];
    float ghn = ws[OFF_GHBUF + 2 * B * HD + (size_t)b * HD + j];
    float hold = ws[OFF_HBUF + (size_t)b * HD + j];
    float r = sigm(gr + ghr);
    float z = sigm(gz + ghz);
    float n = tanhfast(gn + r * ghn);
    ws[OFF_HBUF + (size_t)b * HD + j] = (1.f - z) * n + z * hold;
}

// ---------------- P1: logits = h2@Wout.T + bout ; atomic argmax + expsum ----------------
__global__ __launch_bounds__(256) void k_proj(
    const float* __restrict__ Wout, const float* __restrict__ bout,
    float* __restrict__ ws, float* __restrict__ out, int t)
{
    int v = blockIdx.x * 256 + threadIdx.x;
    bool valid = v < VD;
    const float* hb = ws + OFF_HBUF;
    float acc[B];
    float bo = valid ? bout[v] : 0.f;
#pragma unroll
    for (int b = 0; b < B; b++) acc[b] = bo;
    const float* wrow = Wout + (size_t)(valid ? v : 0) * HD;
    for (int k4 = 0; k4 < HD / 4; k4++) {
        float4 w4 = *(const float4*)&wrow[k4 * 4];
#pragma unroll
        for (int b = 0; b < B; b++) {
            float4 h4 = *(const float4*)&hb[(size_t)b * HD + k4 * 4];
            acc[b] += w4.x * h4.x + w4.y * h4.y + w4.z * h4.z + w4.w * h4.w;
        }
    }
    float* expsum = ws + OFF_EXPSUM + (size_t)t * B;
    unsigned long long* pmax = (unsigned long long*)(ws + OFF_PACKED) + (size_t)t * B;
    int lanei = (int)(threadIdx.x & 63);
#pragma unroll
    for (int b = 0; b < B; b++) {
        float val = valid ? acc[b] : -__builtin_inff();
        unsigned u = __float_as_uint(val);
        u = (u & 0x80000000u) ? ~u : (u | 0x80000000u);
        unsigned long long pk =
            ((unsigned long long)u << 32) | (unsigned)(valid ? (VD - 1 - v) : 0);
        float e = valid ? __expf(acc[b]) : 0.f;
        for (int off = 32; off; off >>= 1) {
            unsigned long long o = __shfl_xor(pk, off);
            pk = (o > pk) ? o : pk;
            e += __shfl_xor(e, off);
        }
        if (lanei == b) { atomicMax(pmax + b, pk); atomicAdd(expsum + b, e); }
        if (valid) out[((size_t)b * T + t) * VD + v] = acc[b];
    }
}

// ---------------- F2: idx, mask, lse ----------------
__global__ void k_fin_small(float* __restrict__ ws, float* __restrict__ out)
{
    int b = threadIdx.x;
    if (b >= B) return;
    const unsigned long long* pmax = (const unsigned long long*)(ws + OFF_PACKED);
    int eos = 0;
    for (int t = 0; t < T; t++) {
        unsigned long long p = pmax[(size_t)t * B + b];
        int v = (VD - 1) - (int)(unsigned)(p & 0xffffffffu);
        out[O_IDX + (size_t)b * T + t] = (float)v;
        if (v == EOS) eos++;
        out[O_MASK + (size_t)b * T + t] = (eos == 0) ? 1.f : 0.f;
        ws[OFF_LSE + (size_t)t * B + b] = logf(ws[OFF_EXPSUM + (size_t)t * B + b]);
    }
}

// ---------------- F1: logp = logits - lse ----------------
__global__ __launch_bounds__(256) void k_logp(
    const float* __restrict__ ws, float* __restrict__ out)
{
    size_t gid = (size_t)blockIdx.x * 256 + threadIdx.x;
    const size_t NQ = (size_t)B * T * (VD / 4);
    if (gid >= NQ) return;
    size_t row = gid / (VD / 4);
    int c4 = (int)(gid - row * (VD / 4));
    int b = (int)(row >> 5), t = (int)(row & 31);
    float L = ws[OFF_LSE + (size_t)t * B + b];
    float4* p = (float4*)(out + row * VD + (size_t)c4 * 4);
    float4 x = *p;
    x.x -= L; x.y -= L; x.z -= L; x.w -= L;
    *p = x;
}

extern "C" void kernel_launch(void* const* d_in, const int* in_sizes, int n_in,
                              void* d_out, int out_size, void* d_ws, size_t ws_size,
                              hipStream_t stream)
{
    (void)in_sizes; (void)n_in; (void)out_size; (void)ws_size;
    const int*   data    = (const int*)d_in[0];
    const float* emb_enc = (const float*)d_in[4];
    const float* emb_dec = (const float*)d_in[5];
    const float* Wihf    = (const float*)d_in[6];
    const float* Whhf    = (const float*)d_in[7];
    const float* bihf    = (const float*)d_in[8];
    const float* bhhf    = (const float*)d_in[9];
    const float* Wihb    = (const float*)d_in[10];
    const float* Whhb    = (const float*)d_in[11];
    const float* bihb    = (const float*)d_in[12];
    const float* bhhb    = (const float*)d_in[13];
    const float* Wihd    = (const float*)d_in[14];
    const float* Whhd    = (const float*)d_in[15];
    const float* bihd    = (const float*)d_in[16];
    const float* bhhd    = (const float*)d_in[17];
    const float* Wattn   = (const float*)d_in[18];
    const float* battn   = (const float*)d_in[19];
    const float* Wout    = (const float*)d_in[20];
    const float* bout    = (const float*)d_in[21];
    float* ws  = (float*)d_ws;
    float* out = (float*)d_out;

    k_prep<<<dim3(12920), dim3(256), 0, stream>>>(Wihf, Whhf, Wihb, Whhb,
                                                  Wihd, Whhd, Wattn, ws);
    k_enc_gi<<<dim3(S, 2, 2), dim3(256), 0, stream>>>(data, emb_enc, bihf, bihb, ws);
    k_enc_rec<<<dim3(B, 2), dim3(256), 0, stream>>>(bhhf, bhhb, ws);

    for (int t = 0; t < T; t++) {
        k_dec1<<<dim3(B, 6), dim3(256), 0, stream>>>(emb_dec, battn, bhhd, bihd, ws, t);
        k_dec_attn<<<dim3(B), dim3(64), 0, stream>>>(ws, out, t);
        k_dec3<<<dim3(16, 4), dim3(256), 0, stream>>>(ws, t);
        k_proj<<<dim3((VD + 255) / 256), dim3(256), 0, stream>>>(Wout, bout, ws, out, t);
    }
    k_fin_small<<<dim3(1), dim3(64), 0, stream>>>(ws, out);
    k_logp<<<dim3((B * T * (VD / 4) + 255) / 256), dim3(256), 0, stream>>>(ws, out);
}

// Round 2
// 7997.533 us; speedup vs baseline: 2.3469x; 2.3469x over previous
//
#include <hip/hip_runtime.h>
#include <stdint.h>

#define B 32
#define S 64
#define T 32
#define E 300
#define HE 256
#define HD 512
#define VD 50000
#define GE 768
#define GD 1536
#define CATN 812
#define SOS 2
#define EOS 3

// ---------------- ws layout (float offsets) ----------------
#define SZ_WIHT3   (E*HE*3)
#define SZ_WHHT3   (HE*HE*3)
#define SZ_WATTNT4 (CATN*HD)
#define SZ_WIHDT3  (CATN*HD*3)
#define SZ_WHHDT3  (HD*HD*3)
#define SZ_GI      (S*B*HE*3)
#define SZ_ENCOUT  (B*S*HD)

constexpr size_t OFF_WIHT3F  = 0;
constexpr size_t OFF_WIHT3B  = OFF_WIHT3F + SZ_WIHT3 + 4;
constexpr size_t OFF_WHHT3F  = OFF_WIHT3B + SZ_WIHT3 + 4;
constexpr size_t OFF_WHHT3B  = OFF_WHHT3F + SZ_WHHT3 + 4;
constexpr size_t OFF_WATTNT4 = OFF_WHHT3B + SZ_WHHT3 + 4;
constexpr size_t OFF_WIHDT3  = OFF_WATTNT4 + SZ_WATTNT4;
constexpr size_t OFF_WHHDT3  = OFF_WIHDT3 + SZ_WIHDT3 + 4;
constexpr size_t OFF_GIF     = OFF_WHHDT3 + SZ_WHHDT3 + 4;
constexpr size_t OFF_GIB     = OFF_GIF + SZ_GI + 4;
constexpr size_t OFF_ENCOUT  = OFF_GIB + SZ_GI + 4;
constexpr size_t OFF_HBUF    = OFF_ENCOUT + SZ_ENCOUT;
constexpr size_t OFF_QBUF    = OFF_HBUF + B*HD;
constexpr size_t OFF_GHBUF   = OFF_QBUF + B*HD;      // [3][B][HD]
constexpr size_t OFF_GIEBUF  = OFF_GHBUF + 3*B*HD;   // [3][B][HD]
constexpr size_t OFF_CTXBUF  = OFF_GIEBUF + 3*B*HD;
constexpr size_t OFF_EXPSUM  = OFF_CTXBUF + B*HD;    // [T][B]
constexpr size_t OFF_LSE     = OFF_EXPSUM + T*B;     // [T][B]
constexpr size_t OFF_PACKED  = OFF_LSE + T*B;        // u64 [T][B] (8B-aligned: offset is even)

// ---------------- d_out layout ----------------
constexpr size_t O_IDX  = (size_t)B*T*VD;
constexpr size_t O_MASK = O_IDX + B*T;
constexpr size_t O_ATT  = O_MASK + B*T;

struct __align__(4) f4u { float x, y, z, w; };
__device__ __forceinline__ f4u ld4u(const float* p) { return *(const f4u*)p; }

__device__ __forceinline__ float sigm(float x) { return 1.0f / (1.0f + __expf(-x)); }
__device__ __forceinline__ float tanhfast(float x) {
    float e = __expf(2.0f * fminf(x, 15.0f));
    return (e - 1.0f) / (e + 1.0f);
}

// ---------------- K0: weight repack + scratch zero ----------------
__global__ __launch_bounds__(256) void k_prep(
    const float* __restrict__ Wihf, const float* __restrict__ Whhf,
    const float* __restrict__ Wihb, const float* __restrict__ Whhb,
    const float* __restrict__ Wihd, const float* __restrict__ Whhd,
    const float* __restrict__ Wattn, float* __restrict__ ws)
{
    const size_t NWIH = (size_t)GE * E;
    const size_t NWHH = (size_t)GE * HE;
    const size_t NATT = (size_t)HD * CATN;
    const size_t NWID = (size_t)GD * CATN;
    const size_t NWHD = (size_t)GD * HD;
    size_t i = (size_t)blockIdx.x * 256 + threadIdx.x;

    if (i < 2 * NWIH) {
        int d = i >= NWIH;
        size_t r = i - (d ? NWIH : 0);
        int row = (int)(r / E), k = (int)(r - (size_t)row * E);
        int g = row >> 8, j = row & 255;
        const float* src = d ? Wihb : Wihf;
        ws[(d ? OFF_WIHT3B : OFF_WIHT3F) + ((size_t)k * HE + j) * 3 + g] = src[r];
        return;
    }
    i -= 2 * NWIH;
    if (i < 2 * NWHH) {
        int d = i >= NWHH;
        size_t r = i - (d ? NWHH : 0);
        int row = (int)(r / HE), k = (int)(r & (HE - 1));
        int g = row >> 8, j = row & 255;
        const float* src = d ? Whhb : Whhf;
        ws[(d ? OFF_WHHT3B : OFF_WHHT3F) + ((size_t)k * HE + j) * 3 + g] = src[r];
        return;
    }
    i -= 2 * NWHH;
    if (i < NATT) {
        int row = (int)(i / CATN), k = (int)(i - (size_t)row * CATN);
        ws[OFF_WATTNT4 + (((size_t)(k >> 2) * HD + row) << 2) + (k & 3)] = Wattn[i];
        return;
    }
    i -= NATT;
    if (i < NWID) {
        int row = (int)(i / CATN), k = (int)(i - (size_t)row * CATN);
        int g = row >> 9, j = row & 511;
        ws[OFF_WIHDT3 + ((size_t)k * HD + j) * 3 + g] = Wihd[i];
        return;
    }
    i -= NWID;
    if (i < NWHD) {
        int row = (int)(i / HD), k = (int)(i & (HD - 1));
        int g = row >> 9, j = row & 511;
        ws[OFF_WHHDT3 + ((size_t)k * HD + j) * 3 + g] = Whhd[i];
        return;
    }
    i -= NWHD;
    if (i < 4096) ws[OFF_EXPSUM + i] = 0.0f;   // expsum + lse + packedmax
}

// ---------------- K1: encoder input gates ----------------
__global__ __launch_bounds__(256) void k_enc_gi(
    const int* __restrict__ data, const float* __restrict__ emb_enc,
    const float* __restrict__ bihf, const float* __restrict__ bihb,
    float* __restrict__ ws)
{
    int s = blockIdx.x, dir = blockIdx.y, b0 = blockIdx.z * 16;
    int tid = threadIdx.x;
    __shared__ float xT[E * 16];
    int s_eff = dir ? (S - 1 - s) : s;
    for (int idx = tid; idx < 16 * E; idx += 256) {
        int bb = idx / E, k = idx - bb * E;
        int tok = data[(b0 + bb) * S + s_eff];
        xT[k * 16 + bb] = emb_enc[(size_t)tok * E + k];
    }
    __syncthreads();
    const float* W3 = ws + (dir ? OFF_WIHT3B : OFF_WIHT3F);
    const float* bih = dir ? bihb : bihf;
    int j = tid;
    float aR[16], aZ[16], aN[16];
#pragma unroll
    for (int bb = 0; bb < 16; bb++) { aR[bb] = 0.f; aZ[bb] = 0.f; aN[bb] = 0.f; }
    for (int k = 0; k < E; k++) {
        f4u w = ld4u(W3 + ((size_t)k * HE + j) * 3);
        const float* xk = &xT[k * 16];
#pragma unroll
        for (int bb = 0; bb < 16; bb++) {
            float x = xk[bb];
            aR[bb] += x * w.x; aZ[bb] += x * w.y; aN[bb] += x * w.z;
        }
    }
    float br = bih[j], bz = bih[HE + j], bn = bih[2 * HE + j];
    float* gi = ws + (dir ? OFF_GIB : OFF_GIF);
#pragma unroll
    for (int bb = 0; bb < 16; bb++) {
        size_t base = (((size_t)s * B + b0 + bb) * HE + j) * 3;
        gi[base + 0] = aR[bb] + br;
        gi[base + 1] = aZ[bb] + bz;
        gi[base + 2] = aN[bb] + bn;
    }
}

// ---------------- K2: encoder recurrence — 1024 threads, k split 4-way ----------------
__global__ __launch_bounds__(1024) void k_enc_rec(
    const float* __restrict__ bhhf, const float* __restrict__ bhhb,
    float* __restrict__ ws)
{
    int b = blockIdx.x, dir = blockIdx.y;
    int tid = threadIdx.x;
    int j = tid & 255, kc = tid >> 8;        // kc in 0..3, 64 k each
    __shared__ float h[2][HE];
    __shared__ float part[3][4][HE];         // [gate][kc][j]
    if (tid < HE) h[0][tid] = 0.f;
    __syncthreads();
    const float* W3 = ws + (dir ? OFF_WHHT3B : OFF_WHHT3F);
    const float* gi = ws + (dir ? OFF_GIB : OFF_GIF);
    const float* bhh = dir ? bhhb : bhhf;
    float* enc = ws + OFF_ENCOUT;
    float br = bhh[j], bz = bhh[HE + j], bn = bhh[2 * HE + j];
    const float* Wp = W3 + ((size_t)(kc * 64) * HE + j) * 3;
    for (int s = 0; s < S; s++) {
        const float* hc = h[s & 1];
        float gr = 0.f, gz = 0.f, gn = 0.f;
#pragma unroll 4
        for (int k4 = 0; k4 < 16; k4++) {
            float4 h4 = *(const float4*)&hc[kc * 64 + k4 * 4];
#pragma unroll
            for (int kk = 0; kk < 4; kk++) {
                f4u w = ld4u(Wp + ((size_t)(k4 * 4 + kk) * HE) * 3);
                float hv = (kk == 0) ? h4.x : (kk == 1) ? h4.y : (kk == 2) ? h4.z : h4.w;
                gr += hv * w.x; gz += hv * w.y; gn += hv * w.z;
            }
        }
        part[0][kc][j] = gr; part[1][kc][j] = gz; part[2][kc][j] = gn;
        __syncthreads();
        if (kc == 0) {
            float sgr = part[0][0][j] + part[0][1][j] + part[0][2][j] + part[0][3][j] + br;
            float sgz = part[1][0][j] + part[1][1][j] + part[1][2][j] + part[1][3][j] + bz;
            float sgn = part[2][0][j] + part[2][1][j] + part[2][2][j] + part[2][3][j] + bn;
            f4u g = ld4u(gi + (((size_t)s * B + b) * HE + j) * 3);
            float hold = hc[j];
            float r = sigm(g.x + sgr);
            float z = sigm(g.y + sgz);
            float n = tanhfast(g.z + r * sgn);
            float hn = (1.f - z) * n + z * hold;
            h[(s + 1) & 1][j] = hn;
            int s_store = dir ? (S - 1 - s) : s;
            enc[((size_t)b * S + s_store) * HD + dir * HE + j] = hn;
            if (s == S - 1) ws[OFF_HBUF + (size_t)b * HD + dir * HE + j] = hn;
        }
        __syncthreads();
    }
}

__device__ __forceinline__ int decode_inp(const float* ws, int t, int b) {
    if (t == 0) return SOS;
    const unsigned long long* pm = (const unsigned long long*)(ws + OFF_PACKED);
    unsigned long long p = pm[(size_t)(t - 1) * B + b];
    return (VD - 1) - (int)(unsigned)(p & 0xffffffffu);
}

// ---------------- D1: q / gh / giE — (j-tile, b-group-of-8, kind) blocks ----------------
__global__ __launch_bounds__(256) void k_dec1(
    const float* __restrict__ emb_dec, const float* __restrict__ battn,
    const float* __restrict__ bhhd, const float* __restrict__ bihd,
    float* __restrict__ ws, int t)
{
    int jc = blockIdx.x, bg = blockIdx.y, kind = blockIdx.z;
    int tid = threadIdx.x;
    int jl = tid & 31, bb8 = tid >> 5;
    int b0 = bg * 8;
    __shared__ float cat[8][816];
    for (int bb = 0; bb < 8; bb++) {
        int inp = decode_inp(ws, t, b0 + bb);
        const float* eb = emb_dec + (size_t)inp * E;
        const float* hb = ws + OFF_HBUF + (size_t)(b0 + bb) * HD;
        for (int k = tid; k < CATN; k += 256)
            cat[bb][k] = (k < E) ? eb[k] : hb[k - E];
    }
    __syncthreads();
    int j = jc * 32 + jl;
    int b = b0 + bb8;
    if (kind == 0) {                 // q = cat(emb,h) @ Wattn.T + battn
        float acc = battn[j];
        const float* W4 = ws + OFF_WATTNT4;
        for (int k4 = 0; k4 < CATN / 4; k4++) {
            float4 c4 = *(const float4*)&cat[bb8][k4 * 4];
            float4 w4 = *(const float4*)&W4[((size_t)k4 * HD + j) << 2];
            acc += c4.x * w4.x + c4.y * w4.y + c4.z * w4.z + c4.w * w4.w;
        }
        ws[OFF_QBUF + (size_t)b * HD + j] = acc;
    } else if (kind == 1) {          // gh = h @ Whhd.T + bhhd
        float gr = bhhd[j], gz = bhhd[HD + j], gn = bhhd[2 * HD + j];
        const float* W3 = ws + OFF_WHHDT3;
        for (int k4 = 0; k4 < HD / 4; k4++) {
            float4 h4 = *(const float4*)&cat[bb8][E + k4 * 4];
#pragma unroll
            for (int kk = 0; kk < 4; kk++) {
                f4u w = ld4u(W3 + ((size_t)(k4 * 4 + kk) * HD + j) * 3);
                float hv = (kk == 0) ? h4.x : (kk == 1) ? h4.y : (kk == 2) ? h4.z : h4.w;
                gr += hv * w.x; gz += hv * w.y; gn += hv * w.z;
            }
        }
        float* gh = ws + OFF_GHBUF;
        gh[0 * B * HD + (size_t)b * HD + j] = gr;
        gh[1 * B * HD + (size_t)b * HD + j] = gz;
        gh[2 * B * HD + (size_t)b * HD + j] = gn;
    } else {                         // giE = emb @ Wihd[:, :E].T + bihd
        float gr = bihd[j], gz = bihd[HD + j], gn = bihd[2 * HD + j];
        const float* W3 = ws + OFF_WIHDT3;
        for (int k4 = 0; k4 < E / 4; k4++) {
            float4 x4 = *(const float4*)&cat[bb8][k4 * 4];
#pragma unroll
            for (int kk = 0; kk < 4; kk++) {
                f4u w = ld4u(W3 + ((size_t)(k4 * 4 + kk) * HD + j) * 3);
                float xv = (kk == 0) ? x4.x : (kk == 1) ? x4.y : (kk == 2) ? x4.z : x4.w;
                gr += xv * w.x; gz += xv * w.y; gn += xv * w.z;
            }
        }
        float* ge = ws + OFF_GIEBUF;
        ge[0 * B * HD + (size_t)b * HD + j] = gr;
        ge[1 * B * HD + (size_t)b * HD + j] = gz;
        ge[2 * B * HD + (size_t)b * HD + j] = gn;
    }
}

// ---------------- D2: scores -> softmax -> ctx (256 threads per batch row) ----------------
__global__ __launch_bounds__(256) void k_dec_attn(
    float* __restrict__ ws, float* __restrict__ out, int t)
{
    int b = blockIdx.x, tid = threadIdx.x;
    __shared__ float q[HD];
    __shared__ float awl[S];
    const float* qb = ws + OFF_QBUF + (size_t)b * HD;
    for (int k = tid; k < HD; k += 256) q[k] = qb[k];
    __syncthreads();
    if (tid < S) {
        int s = tid;
        const float* enc = ws + OFF_ENCOUT + ((size_t)b * S + s) * HD;
        float sc = 0.f;
        for (int k4 = 0; k4 < HD / 4; k4++) {
            float4 q4 = *(const float4*)&q[k4 * 4];
            float4 e4 = *(const float4*)&enc[k4 * 4];
            sc += q4.x * e4.x + q4.y * e4.y + q4.z * e4.z + q4.w * e4.w;
        }
        float m = sc;
        for (int off = 32; off; off >>= 1) m = fmaxf(m, __shfl_xor(m, off));
        float e = __expf(sc - m);
        float sum = e;
        for (int off = 32; off; off >>= 1) sum += __shfl_xor(sum, off);
        float aw = e / sum;
        out[O_ATT + ((size_t)b * T + t) * S + s] = aw;
        awl[s] = aw;
    }
    __syncthreads();
    const float* encb = ws + OFF_ENCOUT + (size_t)b * S * HD;
    float* ctx = ws + OFF_CTXBUF + (size_t)b * HD;
    for (int jj = 0; jj < HD / 256; jj++) {
        int jIdx = jj * 256 + tid;
        float acc = 0.f;
        for (int ss = 0; ss < S; ss++) acc += awl[ss] * encb[(size_t)ss * HD + jIdx];
        ctx[jIdx] = acc;
    }
}

// ---------------- D3: giC = ctx@Wihd[:, E:].T ; gates -> h2 ----------------
__global__ __launch_bounds__(256) void k_dec3(float* __restrict__ ws, int t)
{
    int jc = blockIdx.x, bg = blockIdx.y;
    int tid = threadIdx.x;
    int jl = tid & 31, bb = tid >> 5;
    int j = jc * 32 + jl, b = bg * 8 + bb;
    __shared__ float xc[8 * HD];
    for (int idx = tid; idx < 8 * HD; idx += 256) {
        int bbb = idx >> 9, k = idx & 511;
        xc[idx] = ws[OFF_CTXBUF + (size_t)(bg * 8 + bbb) * HD + k];
    }
    __syncthreads();
    const float* W3 = ws + OFF_WIHDT3;
    float gr = ws[OFF_GIEBUF + 0 * B * HD + (size_t)b * HD + j];
    float gz = ws[OFF_GIEBUF + 1 * B * HD + (size_t)b * HD + j];
    float gn = ws[OFF_GIEBUF + 2 * B * HD + (size_t)b * HD + j];
    const float* xrow = &xc[bb * HD];
    for (int k4 = 0; k4 < HD / 4; k4++) {
        float4 x4 = *(const float4*)&xrow[k4 * 4];
#pragma unroll
        for (int kk = 0; kk < 4; kk++) {
            f4u w = ld4u(W3 + ((size_t)(E + k4 * 4 + kk) * HD + j) * 3);
            float xv = (kk == 0) ? x4.x : (kk == 1) ? x4.y : (kk == 2) ? x4.z : x4.w;
            gr += xv * w.x; gz += xv * w.y; gn += xv * w.z;
        }
    }
    float ghr = ws[OFF_GHBUF + 0 * B * HD + (size_t)b * HD + j];
    float ghz = ws[OFF_GHBUF + 1 * B * HD + (size_t)b * HD + j];
    float ghn = ws[OFF_GHBUF + 2 * B * HD + (size_t)b * HD + j];
    float hold = ws[OFF_HBUF + (size_t)b * HD + j];
    float r = sigm(gr + ghr);
    float z = sigm(gz + ghz);
    float n = tanhfast(gn + r * ghn);
    ws[OFF_HBUF + (size_t)b * HD + j] = (1.f - z) * n + z * hold;
}

// ---------------- P1: logits + argmax + expsum — (v-tile, b-group-of-8) ----------------
__global__ __launch_bounds__(256) void k_proj(
    const float* __restrict__ Wout, const float* __restrict__ bout,
    float* __restrict__ ws, float* __restrict__ out, int t)
{
    int v = blockIdx.x * 256 + threadIdx.x;
    int b0 = blockIdx.y * 8;
    bool valid = v < VD;
    __shared__ float hl[8 * HD];                 // 16 KB
    __shared__ float red_e[4][8];
    __shared__ unsigned long long red_m[4][8];
    const float* hb = ws + OFF_HBUF;
    for (int idx = threadIdx.x; idx < 8 * HD; idx += 256)
        hl[idx] = hb[(size_t)(b0 + (idx >> 9)) * HD + (idx & 511)];
    __syncthreads();

    float acc[8];
    float bo = valid ? bout[v] : 0.f;
#pragma unroll
    for (int bb = 0; bb < 8; bb++) acc[bb] = bo;
    const float* wrow = Wout + (size_t)(valid ? v : 0) * HD;
    for (int k4 = 0; k4 < HD / 4; k4++) {
        float4 w4 = *(const float4*)&wrow[k4 * 4];
#pragma unroll
        for (int bb = 0; bb < 8; bb++) {
            float4 h4 = *(const float4*)&hl[bb * HD + k4 * 4];
            acc[bb] = fmaf(w4.x, h4.x, fmaf(w4.y, h4.y,
                      fmaf(w4.z, h4.z, fmaf(w4.w, h4.w, acc[bb]))));
        }
    }
    if (valid) {
#pragma unroll
        for (int bb = 0; bb < 8; bb++)
            out[((size_t)(b0 + bb) * T + t) * VD + v] = acc[bb];
    }
    int wv = threadIdx.x >> 6, lane = threadIdx.x & 63;
#pragma unroll
    for (int bb = 0; bb < 8; bb++) {
        float val = valid ? acc[bb] : -__builtin_inff();
        unsigned u = __float_as_uint(val);
        u = (u & 0x80000000u) ? ~u : (u | 0x80000000u);
        unsigned long long pk =
            ((unsigned long long)u << 32) | (unsigned)(valid ? (VD - 1 - v) : 0);
        float e = valid ? __expf(acc[bb]) : 0.f;
        for (int off = 32; off; off >>= 1) {
            unsigned long long o = __shfl_xor(pk, off);
            pk = (o > pk) ? o : pk;
            e += __shfl_xor(e, off);
        }
        if (lane == 0) { red_e[wv][bb] = e; red_m[wv][bb] = pk; }
    }
    __syncthreads();
    if (threadIdx.x < 8) {
        int bb = threadIdx.x;
        float e = red_e[0][bb] + red_e[1][bb] + red_e[2][bb] + red_e[3][bb];
        unsigned long long pk = red_m[0][bb];
        pk = red_m[1][bb] > pk ? red_m[1][bb] : pk;
        pk = red_m[2][bb] > pk ? red_m[2][bb] : pk;
        pk = red_m[3][bb] > pk ? red_m[3][bb] : pk;
        atomicAdd(ws + OFF_EXPSUM + (size_t)t * B + b0 + bb, e);
        atomicMax((unsigned long long*)(ws + OFF_PACKED) + (size_t)t * B + b0 + bb, pk);
    }
}

// ---------------- F2: idx, mask, lse ----------------
__global__ void k_fin_small(float* __restrict__ ws, float* __restrict__ out)
{
    int b = threadIdx.x;
    if (b >= B) return;
    const unsigned long long* pmax = (const unsigned long long*)(ws + OFF_PACKED);
    int eos = 0;
    for (int t = 0; t < T; t++) {
        unsigned long long p = pmax[(size_t)t * B + b];
        int v = (VD - 1) - (int)(unsigned)(p & 0xffffffffu);
        out[O_IDX + (size_t)b * T + t] = (float)v;
        if (v == EOS) eos++;
        out[O_MASK + (size_t)b * T + t] = (eos == 0) ? 1.f : 0.f;
        ws[OFF_LSE + (size_t)t * B + b] = logf(ws[OFF_EXPSUM + (size_t)t * B + b]);
    }
}

// ---------------- F1: logp = logits - lse ----------------
__global__ __launch_bounds__(256) void k_logp(
    const float* __restrict__ ws, float* __restrict__ out)
{
    size_t gid = (size_t)blockIdx.x * 256 + threadIdx.x;
    const size_t NQ = (size_t)B * T * (VD / 4);
    if (gid >= NQ) return;
    size_t row = gid / (VD / 4);
    int c4 = (int)(gid - row * (VD / 4));
    int b = (int)(row >> 5), t = (int)(row & 31);
    float L = ws[OFF_LSE + (size_t)t * B + b];
    float4* p = (float4*)(out + row * VD + (size_t)c4 * 4);
    float4 x = *p;
    x.x -= L; x.y -= L; x.z -= L; x.w -= L;
    *p = x;
}

extern "C" void kernel_launch(void* const* d_in, const int* in_sizes, int n_in,
                              void* d_out, int out_size, void* d_ws, size_t ws_size,
                              hipStream_t stream)
{
    (void)in_sizes; (void)n_in; (void)out_size; (void)ws_size;
    const int*   data    = (const int*)d_in[0];
    const float* emb_enc = (const float*)d_in[4];
    const float* emb_dec = (const float*)d_in[5];
    const float* Wihf    = (const float*)d_in[6];
    const float* Whhf    = (const float*)d_in[7];
    const float* bihf    = (const float*)d_in[8];
    const float* bhhf    = (const float*)d_in[9];
    const float* Wihb    = (const float*)d_in[10];
    const float* Whhb    = (const float*)d_in[11];
    const float* bihb    = (const float*)d_in[12];
    const float* bhhb    = (const float*)d_in[13];
    const float* Wihd    = (const float*)d_in[14];
    const float* Whhd    = (const float*)d_in[15];
    const float* bihd    = (const float*)d_in[16];
    const float* bhhd    = (const float*)d_in[17];
    const float* Wattn   = (const float*)d_in[18];
    const float* battn   = (const float*)d_in[19];
    const float* Wout    = (const float*)d_in[20];
    const float* bout    = (const float*)d_in[21];
    float* ws  = (float*)d_ws;
    float* out = (float*)d_out;

    k_prep<<<dim3(12920), dim3(256), 0, stream>>>(Wihf, Whhf, Wihb, Whhb,
                                                  Wihd, Whhd, Wattn, ws);
    k_enc_gi<<<dim3(S, 2, 2), dim3(256), 0, stream>>>(data, emb_enc, bihf, bihb, ws);
    k_enc_rec<<<dim3(B, 2), dim3(1024), 0, stream>>>(bhhf, bhhb, ws);

    for (int t = 0; t < T; t++) {
        k_dec1<<<dim3(16, 4, 3), dim3(256), 0, stream>>>(emb_dec, battn, bhhd, bihd, ws, t);
        k_dec_attn<<<dim3(B), dim3(256), 0, stream>>>(ws, out, t);
        k_dec3<<<dim3(16, 4), dim3(256), 0, stream>>>(ws, t);
        k_proj<<<dim3((VD + 255) / 256, 4), dim3(256), 0, stream>>>(Wout, bout, ws, out, t);
    }
    k_fin_small<<<dim3(1), dim3(64), 0, stream>>>(ws, out);
    k_logp<<<dim3((B * T * (VD / 4) + 255) / 256), dim3(256), 0, stream>>>(ws, out);
}